// Round 1
// baseline (733.075 us; speedup 1.0000x reference)
//
#include <hip/hip_runtime.h>
#include <math.h>

#define B_    4
#define NF    300
#define QD    512
#define HID   512
#define NH    8
#define HD    64
#define HW    6400      // 80*80
#define ROWS  2400      // NF*NH
#define PB    15360000  // ROWS*HW per batch
#define NORM_FACT 0.125f
#define NEG_INF (-INFINITY)

// ---------------- K1: q projection  qh[b][q][e] = (q . q_w[e]) * 0.125 ----
__global__ __launch_bounds__(256) void qproj_kernel(
    const float* __restrict__ q, const float* __restrict__ qw,
    const float* __restrict__ qb, float* __restrict__ qh)
{
    __shared__ float qs[4][QD];
    const int r0 = blockIdx.x * 4;   // 4 rows (b*NF+q flattened) per block
    const int t  = threadIdx.x;
    #pragma unroll
    for (int row = 0; row < 4; ++row) {
        qs[row][t]       = q[(size_t)(r0 + row) * QD + t];
        qs[row][t + 256] = q[(size_t)(r0 + row) * QD + t + 256];
    }
    __syncthreads();
    #pragma unroll
    for (int eo = 0; eo < 2; ++eo) {
        const int e = t + eo * 256;
        float a0 = 0.f, a1 = 0.f, a2 = 0.f, a3 = 0.f;
        for (int d = 0; d < QD; d += 4) {
            float4 w = *(const float4*)&qw[(size_t)e * QD + d];
            a0 += qs[0][d]*w.x + qs[0][d+1]*w.y + qs[0][d+2]*w.z + qs[0][d+3]*w.w;
            a1 += qs[1][d]*w.x + qs[1][d+1]*w.y + qs[1][d+2]*w.z + qs[1][d+3]*w.w;
            a2 += qs[2][d]*w.x + qs[2][d+1]*w.y + qs[2][d+2]*w.z + qs[2][d+3]*w.w;
            a3 += qs[3][d]*w.x + qs[3][d+1]*w.y + qs[3][d+2]*w.z + qs[3][d+3]*w.w;
        }
        const float bias = qb[e];
        qh[(size_t)(r0+0)*HID + e] = (a0 + bias) * NORM_FACT;
        qh[(size_t)(r0+1)*HID + e] = (a1 + bias) * NORM_FACT;
        qh[(size_t)(r0+2)*HID + e] = (a2 + bias) * NORM_FACT;
        qh[(size_t)(r0+3)*HID + e] = (a3 + bias) * NORM_FACT;
    }
}

// ---------------- K2: k projection  kp[b][e][p] = k_w[e] . k[b][:][p] + k_b[e]
// per-batch GEMM: C[512e][6400p] = W[512][512] * K[512][6400]
__global__ __launch_bounds__(256) void kproj_kernel(
    const float* __restrict__ k, const float* __restrict__ kw,
    const float* __restrict__ kb, float* __restrict__ kp)
{
    __shared__ __align__(16) float As[8][132];  // [d][e] transposed tile
    __shared__ __align__(16) float Bs[8][128];  // [d][p]
    const int b  = blockIdx.z;
    const int e0 = blockIdx.y * 128;
    const int p0 = blockIdx.x * 128;
    const int t  = threadIdx.x;
    const int tx = t & 15, ty = t >> 4;
    const float* kB = k + (size_t)b * QD * HW;

    float acc[8][8] = {};
    for (int d0 = 0; d0 < QD; d0 += 8) {
        #pragma unroll
        for (int i = 0; i < 4; ++i) {
            int idx = t + i * 256;
            int e = idx >> 3, d = idx & 7;
            As[d][e] = kw[(size_t)(e0 + e) * QD + d0 + d];
        }
        #pragma unroll
        for (int i = 0; i < 4; ++i) {
            int idx = t + i * 256;
            int d = idx >> 7, p = idx & 127;
            Bs[d][p] = kB[(size_t)(d0 + d) * HW + p0 + p];
        }
        __syncthreads();
        #pragma unroll
        for (int d = 0; d < 8; ++d) {
            float4 A0 = *(const float4*)&As[d][ty * 4];
            float4 A1 = *(const float4*)&As[d][64 + ty * 4];
            float4 B0 = *(const float4*)&Bs[d][tx * 4];
            float4 B1 = *(const float4*)&Bs[d][64 + tx * 4];
            float av[8] = {A0.x,A0.y,A0.z,A0.w,A1.x,A1.y,A1.z,A1.w};
            float bv[8] = {B0.x,B0.y,B0.z,B0.w,B1.x,B1.y,B1.z,B1.w};
            #pragma unroll
            for (int i = 0; i < 8; ++i)
                #pragma unroll
                for (int j = 0; j < 8; ++j)
                    acc[i][j] += av[i] * bv[j];
        }
        __syncthreads();
    }
    #pragma unroll
    for (int i = 0; i < 8; ++i) {
        const int e = e0 + ((i < 4) ? (ty * 4 + i) : (64 + ty * 4 + i - 4));
        const float bias = kb[e];
        float* dst = kp + (size_t)b * HID * HW + (size_t)e * HW + p0;
        float4 v0 = make_float4(acc[i][0]+bias, acc[i][1]+bias, acc[i][2]+bias, acc[i][3]+bias);
        float4 v1 = make_float4(acc[i][4]+bias, acc[i][5]+bias, acc[i][6]+bias, acc[i][7]+bias);
        *(float4*)&dst[tx * 4]      = v0;
        *(float4*)&dst[64 + tx * 4] = v1;
    }
}

// ---------------- K3: scores + mask + block-level online softmax partials --
// per (b,n): S[300q][6400p] = qh[b,:,n*64:+64] * kp[b,n*64:+64,:]
__global__ __launch_bounds__(256) void scores_kernel(
    const float* __restrict__ qh, const float* __restrict__ kp,
    const int* __restrict__ mask, float* __restrict__ out,
    float* __restrict__ partials)
{
    __shared__ __align__(16) float As[8][132];  // [c][q]
    __shared__ __align__(16) float Bs[8][128];  // [c][p]
    __shared__ float redM[256];
    __shared__ float redS[256];
    const int z  = blockIdx.z;
    const int b  = z >> 3, n = z & 7;
    const int q0 = blockIdx.y * 128;
    const int p0 = blockIdx.x * 128;
    const int t  = threadIdx.x;
    const int tx = t & 15, ty = t >> 4;

    float acc[8][8] = {};
    for (int c0 = 0; c0 < HD; c0 += 8) {
        #pragma unroll
        for (int i = 0; i < 4; ++i) {
            int idx = t + i * 256;
            int qq = idx >> 3, c = idx & 7;
            int qg = q0 + qq;
            As[c][qq] = (qg < NF)
                ? qh[(size_t)(b * NF + qg) * HID + n * HD + c0 + c] : 0.f;
        }
        #pragma unroll
        for (int i = 0; i < 4; ++i) {
            int idx = t + i * 256;
            int c = idx >> 7, p = idx & 127;
            Bs[c][p] = kp[(size_t)b * HID * HW + (size_t)(n * HD + c0 + c) * HW + p0 + p];
        }
        __syncthreads();
        #pragma unroll
        for (int d = 0; d < 8; ++d) {
            float4 A0 = *(const float4*)&As[d][ty * 4];
            float4 A1 = *(const float4*)&As[d][64 + ty * 4];
            float4 B0 = *(const float4*)&Bs[d][tx * 4];
            float4 B1 = *(const float4*)&Bs[d][64 + tx * 4];
            float av[8] = {A0.x,A0.y,A0.z,A0.w,A1.x,A1.y,A1.z,A1.w};
            float bv[8] = {B0.x,B0.y,B0.z,B0.w,B1.x,B1.y,B1.z,B1.w};
            #pragma unroll
            for (int i = 0; i < 8; ++i)
                #pragma unroll
                for (int j = 0; j < 8; ++j)
                    acc[i][j] += av[i] * bv[j];
        }
        __syncthreads();
    }

    // mask flags for this thread's 8 columns
    bool msk[8];
    #pragma unroll
    for (int j = 0; j < 4; ++j) {
        msk[j]     = mask[b * HW + p0 + tx * 4 + j] != 0;
        msk[4 + j] = mask[b * HW + p0 + 64 + tx * 4 + j] != 0;
    }

    // thread-local max over valid (row<NF, unmasked) entries
    float tm = NEG_INF;
    #pragma unroll
    for (int i = 0; i < 8; ++i) {
        int qg = q0 + ((i < 4) ? (ty * 4 + i) : (64 + ty * 4 + i - 4));
        if (qg < NF) {
            #pragma unroll
            for (int j = 0; j < 8; ++j) {
                float v = msk[j] ? NEG_INF : acc[i][j];
                tm = fmaxf(tm, v);
            }
        }
    }
    float ts = 0.f;
    if (tm != NEG_INF) {
        #pragma unroll
        for (int i = 0; i < 8; ++i) {
            int qg = q0 + ((i < 4) ? (ty * 4 + i) : (64 + ty * 4 + i - 4));
            if (qg < NF) {
                #pragma unroll
                for (int j = 0; j < 8; ++j)
                    ts += msk[j] ? 0.f : __expf(acc[i][j] - tm);
            }
        }
    }

    // store raw (masked) scores to d_out
    #pragma unroll
    for (int i = 0; i < 8; ++i) {
        int qg = q0 + ((i < 4) ? (ty * 4 + i) : (64 + ty * 4 + i - 4));
        if (qg < NF) {
            const int row = b * ROWS + qg * NH + n;
            float* dst = out + (size_t)row * HW + p0;
            float4 v0 = make_float4(msk[0] ? NEG_INF : acc[i][0],
                                    msk[1] ? NEG_INF : acc[i][1],
                                    msk[2] ? NEG_INF : acc[i][2],
                                    msk[3] ? NEG_INF : acc[i][3]);
            float4 v1 = make_float4(msk[4] ? NEG_INF : acc[i][4],
                                    msk[5] ? NEG_INF : acc[i][5],
                                    msk[6] ? NEG_INF : acc[i][6],
                                    msk[7] ? NEG_INF : acc[i][7]);
            *(float4*)&dst[tx * 4]      = v0;
            *(float4*)&dst[64 + tx * 4] = v1;
        }
    }

    // block reduce (m, s) online-softmax pairs
    redM[t] = tm; redS[t] = ts;
    __syncthreads();
    for (int off = 128; off > 0; off >>= 1) {
        if (t < off) {
            float m1 = redM[t],       s1 = redS[t];
            float m2 = redM[t + off], s2 = redS[t + off];
            float M = fmaxf(m1, m2);
            float s = (M == NEG_INF) ? 0.f
                      : (s1 * __expf(m1 - M) + s2 * __expf(m2 - M));
            redM[t] = M; redS[t] = s;
        }
        __syncthreads();
    }
    if (t == 0) {
        int lin = (z * gridDim.y + blockIdx.y) * gridDim.x + blockIdx.x;
        partials[2 * lin]     = redM[0];
        partials[2 * lin + 1] = redS[0];
    }
}

// ---------------- K4: merge partials per batch -> (M_b, 1/S_b) -------------
__global__ __launch_bounds__(256) void stats_kernel(
    const float* __restrict__ partials, float* __restrict__ stats, int nper)
{
    __shared__ float redM[256];
    __shared__ float redS[256];
    const int b = blockIdx.x, t = threadIdx.x;
    const float* p = partials + (size_t)b * nper * 2;
    float m = NEG_INF, s = 0.f;
    for (int i = t; i < nper; i += 256) {
        float m2 = p[2 * i], s2 = p[2 * i + 1];
        float M = fmaxf(m, m2);
        float ns = (M == NEG_INF) ? 0.f
                   : (s * __expf(m - M) + s2 * __expf(m2 - M));
        m = M; s = ns;
    }
    redM[t] = m; redS[t] = s;
    __syncthreads();
    for (int off = 128; off > 0; off >>= 1) {
        if (t < off) {
            float m1 = redM[t],       s1 = redS[t];
            float m2 = redM[t + off], s2 = redS[t + off];
            float M = fmaxf(m1, m2);
            float ns = (M == NEG_INF) ? 0.f
                       : (s1 * __expf(m1 - M) + s2 * __expf(m2 - M));
            redM[t] = M; redS[t] = ns;
        }
        __syncthreads();
    }
    if (t == 0) {
        stats[2 * b]     = redM[0];
        stats[2 * b + 1] = 1.0f / redS[0];
    }
}

// ---------------- K5: normalize out = exp(s - M) / S ----------------------
__global__ __launch_bounds__(256) void norm_kernel(
    float* __restrict__ out, const float* __restrict__ stats)
{
    const int i4 = blockIdx.x * 256 + threadIdx.x;   // float4 index
    if (i4 >= (B_ * PB) / 4) return;
    const int b = i4 / (PB / 4);
    const float M    = stats[2 * b];
    const float invS = stats[2 * b + 1];
    float4 v = ((const float4*)out)[i4];
    v.x = __expf(v.x - M) * invS;
    v.y = __expf(v.y - M) * invS;
    v.z = __expf(v.z - M) * invS;
    v.w = __expf(v.w - M) * invS;
    ((float4*)out)[i4] = v;
}

extern "C" void kernel_launch(void* const* d_in, const int* in_sizes, int n_in,
                              void* d_out, int out_size, void* d_ws, size_t ws_size,
                              hipStream_t stream) {
    const float* q    = (const float*)d_in[0];  // [4,300,512]
    const float* k    = (const float*)d_in[1];  // [4,512,80,80]
    const int*   mask = (const int*)  d_in[2];  // [4,80,80] bool->int
    const float* qw   = (const float*)d_in[3];  // [512,512]
    const float* qb   = (const float*)d_in[4];  // [512]
    const float* kw   = (const float*)d_in[5];  // [512,512]
    const float* kb   = (const float*)d_in[6];  // [512]
    float* out = (float*)d_out;                 // [4,1,2400,80,80]
    float* ws  = (float*)d_ws;

    float* qh       = ws;              // 614,400 floats
    float* kp       = ws + 614400;     // 13,107,200 floats
    float* partials = ws + 13721600;   // 4800*2 floats
    float* stats    = ws + 13731200;   // 8 floats

    qproj_kernel<<<300, 256, 0, stream>>>(q, qw, qb, qh);
    kproj_kernel<<<dim3(50, 4, 4), 256, 0, stream>>>(k, kw, kb, kp);
    scores_kernel<<<dim3(50, 3, 32), 256, 0, stream>>>(qh, kp, mask, out, partials);
    stats_kernel<<<4, 256, 0, stream>>>(partials, stats, 1200);
    norm_kernel<<<60000, 256, 0, stream>>>(out, stats);
}

// Round 2
// 563.380 us; speedup vs baseline: 1.3012x; 1.3012x over previous
//
#include <hip/hip_runtime.h>
#include <math.h>

#define B_    4
#define NF    300
#define QD    512
#define HID   512
#define NH    8
#define HD    64
#define HW    6400      // 80*80
#define ROWS  2400      // NF*NH
#define PB    15360000  // ROWS*HW per batch
#define NORM_FACT 0.125f
#define NEG_INF (-INFINITY)
#define LDK   40        // padded LDS row (bf16 elems) for a 32-wide k-chunk; 80B rows keep b128 reads aligned

typedef __bf16 bf16_t;
typedef __bf16 bf16x4_t __attribute__((ext_vector_type(4)));
typedef __bf16 bf16x8_t __attribute__((ext_vector_type(8)));
typedef float  f32x4    __attribute__((ext_vector_type(4)));

__device__ __forceinline__ void splitf(float x, bf16_t& h, bf16_t& l) {
    h = (bf16_t)x;
    l = (bf16_t)(x - (float)h);
}

// ---------------- K1: q projection  qh[b][q][e] = (q . q_w[e] + b) * 0.125 ----
__global__ __launch_bounds__(256) void qproj_kernel(
    const float* __restrict__ q, const float* __restrict__ qw,
    const float* __restrict__ qb, float* __restrict__ qh)
{
    __shared__ float qs[4][QD];
    const int r0 = blockIdx.x * 4;
    const int t  = threadIdx.x;
    #pragma unroll
    for (int row = 0; row < 4; ++row) {
        qs[row][t]       = q[(size_t)(r0 + row) * QD + t];
        qs[row][t + 256] = q[(size_t)(r0 + row) * QD + t + 256];
    }
    __syncthreads();
    #pragma unroll
    for (int eo = 0; eo < 2; ++eo) {
        const int e = t + eo * 256;
        float a0 = 0.f, a1 = 0.f, a2 = 0.f, a3 = 0.f;
        for (int d = 0; d < QD; d += 4) {
            float4 w = *(const float4*)&qw[(size_t)e * QD + d];
            a0 += qs[0][d]*w.x + qs[0][d+1]*w.y + qs[0][d+2]*w.z + qs[0][d+3]*w.w;
            a1 += qs[1][d]*w.x + qs[1][d+1]*w.y + qs[1][d+2]*w.z + qs[1][d+3]*w.w;
            a2 += qs[2][d]*w.x + qs[2][d+1]*w.y + qs[2][d+2]*w.z + qs[2][d+3]*w.w;
            a3 += qs[3][d]*w.x + qs[3][d+1]*w.y + qs[3][d+2]*w.z + qs[3][d+3]*w.w;
        }
        const float bias = qb[e];
        qh[(size_t)(r0+0)*HID + e] = (a0 + bias) * NORM_FACT;
        qh[(size_t)(r0+1)*HID + e] = (a1 + bias) * NORM_FACT;
        qh[(size_t)(r0+2)*HID + e] = (a2 + bias) * NORM_FACT;
        qh[(size_t)(r0+3)*HID + e] = (a3 + bias) * NORM_FACT;
    }
}

// ---------------- K2: k projection via split-bf16 MFMA ---------------------
// per-batch GEMM: kp[512e][6400p] = W[512e][512d] * K[512d][6400p] + kb
__global__ __launch_bounds__(256) void kproj_mfma(
    const float* __restrict__ k, const float* __restrict__ kw,
    const float* __restrict__ kb, float* __restrict__ kp)
{
    __shared__ __align__(16) bf16_t Ah[128][LDK];
    __shared__ __align__(16) bf16_t Al[128][LDK];
    __shared__ __align__(16) bf16_t Bh[128][LDK];
    __shared__ __align__(16) bf16_t Bl[128][LDK];
    const int b  = blockIdx.z;
    const int e0 = blockIdx.y * 128;
    const int p0 = blockIdx.x * 128;
    const int t  = threadIdx.x;
    const int wave = t >> 6, lane = t & 63;
    const int wr = wave >> 1, wc = wave & 1;      // wave's 64x64 quadrant
    const int lm = lane & 15, lq = lane >> 4;
    const float* kB = k + (size_t)b * QD * HW;

    f32x4 acc[4][4];
    const f32x4 zero4 = {0.f, 0.f, 0.f, 0.f};
    #pragma unroll
    for (int i = 0; i < 4; ++i)
        #pragma unroll
        for (int j = 0; j < 4; ++j) acc[i][j] = zero4;

    for (int d0 = 0; d0 < QD; d0 += 32) {
        // stage A = W tile [128e][32d], k-contiguous rows
        #pragma unroll
        for (int i = 0; i < 4; ++i) {
            int idx = t + i * 256;
            int e = idx >> 3, dp = (idx & 7) << 2;
            float4 v = *(const float4*)&kw[(size_t)(e0 + e) * QD + d0 + dp];
            bf16x4_t hv, lv; bf16_t hx, lx;
            splitf(v.x, hx, lx); hv[0] = hx; lv[0] = lx;
            splitf(v.y, hx, lx); hv[1] = hx; lv[1] = lx;
            splitf(v.z, hx, lx); hv[2] = hx; lv[2] = lx;
            splitf(v.w, hx, lx); hv[3] = hx; lv[3] = lx;
            *(bf16x4_t*)&Ah[e][dp] = hv;
            *(bf16x4_t*)&Al[e][dp] = lv;
        }
        // stage B = K tile [32d][128p] -> LDS transposed [p][d] (k-contiguous)
        #pragma unroll
        for (int i = 0; i < 4; ++i) {
            int idx = t + i * 256;
            int p = idx & 127, db = (idx >> 7) << 2;
            bf16x4_t hv, lv;
            #pragma unroll
            for (int j = 0; j < 4; ++j) {
                float x = kB[(size_t)(d0 + db + j) * HW + p0 + p];
                bf16_t hx, lx; splitf(x, hx, lx);
                hv[j] = hx; lv[j] = lx;
            }
            *(bf16x4_t*)&Bh[p][db] = hv;
            *(bf16x4_t*)&Bl[p][db] = lv;
        }
        __syncthreads();

        bf16x8_t ah[4], al[4], bh[4], bl[4];
        #pragma unroll
        for (int mt = 0; mt < 4; ++mt) {
            int r = wr * 64 + mt * 16 + lm;
            ah[mt] = *(const bf16x8_t*)&Ah[r][lq * 8];
            al[mt] = *(const bf16x8_t*)&Al[r][lq * 8];
        }
        #pragma unroll
        for (int nt = 0; nt < 4; ++nt) {
            int c = wc * 64 + nt * 16 + lm;
            bh[nt] = *(const bf16x8_t*)&Bh[c][lq * 8];
            bl[nt] = *(const bf16x8_t*)&Bl[c][lq * 8];
        }
        #pragma unroll
        for (int mt = 0; mt < 4; ++mt)
            #pragma unroll
            for (int nt = 0; nt < 4; ++nt) {
                f32x4 a = acc[mt][nt];
                a = __builtin_amdgcn_mfma_f32_16x16x32_bf16(al[mt], bh[nt], a, 0, 0, 0);
                a = __builtin_amdgcn_mfma_f32_16x16x32_bf16(ah[mt], bl[nt], a, 0, 0, 0);
                a = __builtin_amdgcn_mfma_f32_16x16x32_bf16(ah[mt], bh[nt], a, 0, 0, 0);
                acc[mt][nt] = a;
            }
        __syncthreads();
    }

    // epilogue: C row = e (lq*4+reg within 16-tile), col = p (lm)
    #pragma unroll
    for (int mt = 0; mt < 4; ++mt) {
        #pragma unroll
        for (int reg = 0; reg < 4; ++reg) {
            int e = e0 + wr * 64 + mt * 16 + lq * 4 + reg;
            float bias = kb[e];
            float* dst = kp + (size_t)b * HID * HW + (size_t)e * HW + p0 + wc * 64 + lm;
            #pragma unroll
            for (int nt = 0; nt < 4; ++nt)
                dst[nt * 16] = acc[mt][nt][reg] + bias;
        }
    }
}

// ---------------- K3: scores via split-bf16 MFMA + mask + softmax partials --
// per (b,n): S[300q][6400p] = qh[b,:,n*64:+64] * kp[b,n*64:+64,:]
__global__ __launch_bounds__(256) void scores_mfma(
    const float* __restrict__ qh, const float* __restrict__ kp,
    const int* __restrict__ mask, float* __restrict__ out,
    float* __restrict__ partials)
{
    __shared__ __align__(16) bf16_t Ah[128][LDK];
    __shared__ __align__(16) bf16_t Al[128][LDK];
    __shared__ __align__(16) bf16_t Bh[128][LDK];
    __shared__ __align__(16) bf16_t Bl[128][LDK];
    const int z  = blockIdx.z;
    const int b  = z >> 3, n = z & 7;
    const int q0 = blockIdx.y * 128;
    const int p0 = blockIdx.x * 128;
    const int t  = threadIdx.x;
    const int wave = t >> 6, lane = t & 63;
    const int wr = wave >> 1, wc = wave & 1;
    const int lm = lane & 15, lq = lane >> 4;

    f32x4 acc[4][4];
    const f32x4 zero4 = {0.f, 0.f, 0.f, 0.f};
    #pragma unroll
    for (int i = 0; i < 4; ++i)
        #pragma unroll
        for (int j = 0; j < 4; ++j) acc[i][j] = zero4;

    for (int d0 = 0; d0 < HD; d0 += 32) {  // 2 k-chunks
        // stage A = qh tile [128q][32c], zero-padded past q=299
        #pragma unroll
        for (int i = 0; i < 4; ++i) {
            int idx = t + i * 256;
            int qq = idx >> 3, dp = (idx & 7) << 2;
            int qg = q0 + qq;
            float4 v = make_float4(0.f, 0.f, 0.f, 0.f);
            if (qg < NF)
                v = *(const float4*)&qh[(size_t)(b * NF + qg) * HID + n * HD + d0 + dp];
            bf16x4_t hv, lv; bf16_t hx, lx;
            splitf(v.x, hx, lx); hv[0] = hx; lv[0] = lx;
            splitf(v.y, hx, lx); hv[1] = hx; lv[1] = lx;
            splitf(v.z, hx, lx); hv[2] = hx; lv[2] = lx;
            splitf(v.w, hx, lx); hv[3] = hx; lv[3] = lx;
            *(bf16x4_t*)&Ah[qq][dp] = hv;
            *(bf16x4_t*)&Al[qq][dp] = lv;
        }
        // stage B = kp tile [32c][128p] -> LDS transposed [p][c]
        const float* kpB = kp + (size_t)b * HID * HW + (size_t)(n * HD + d0) * HW;
        #pragma unroll
        for (int i = 0; i < 4; ++i) {
            int idx = t + i * 256;
            int p = idx & 127, db = (idx >> 7) << 2;
            bf16x4_t hv, lv;
            #pragma unroll
            for (int j = 0; j < 4; ++j) {
                float x = kpB[(size_t)(db + j) * HW + p0 + p];
                bf16_t hx, lx; splitf(x, hx, lx);
                hv[j] = hx; lv[j] = lx;
            }
            *(bf16x4_t*)&Bh[p][db] = hv;
            *(bf16x4_t*)&Bl[p][db] = lv;
        }
        __syncthreads();

        bf16x8_t ah[4], al[4], bh[4], bl[4];
        #pragma unroll
        for (int mt = 0; mt < 4; ++mt) {
            int r = wr * 64 + mt * 16 + lm;
            ah[mt] = *(const bf16x8_t*)&Ah[r][lq * 8];
            al[mt] = *(const bf16x8_t*)&Al[r][lq * 8];
        }
        #pragma unroll
        for (int nt = 0; nt < 4; ++nt) {
            int c = wc * 64 + nt * 16 + lm;
            bh[nt] = *(const bf16x8_t*)&Bh[c][lq * 8];
            bl[nt] = *(const bf16x8_t*)&Bl[c][lq * 8];
        }
        #pragma unroll
        for (int mt = 0; mt < 4; ++mt)
            #pragma unroll
            for (int nt = 0; nt < 4; ++nt) {
                f32x4 a = acc[mt][nt];
                a = __builtin_amdgcn_mfma_f32_16x16x32_bf16(al[mt], bh[nt], a, 0, 0, 0);
                a = __builtin_amdgcn_mfma_f32_16x16x32_bf16(ah[mt], bl[nt], a, 0, 0, 0);
                a = __builtin_amdgcn_mfma_f32_16x16x32_bf16(ah[mt], bh[nt], a, 0, 0, 0);
                acc[mt][nt] = a;
            }
        __syncthreads();
    }

    // mask per column tile
    int mm[4];
    #pragma unroll
    for (int nt = 0; nt < 4; ++nt)
        mm[nt] = mask[b * HW + p0 + wc * 64 + nt * 16 + lm];

    // thread-local online-softmax partials over valid entries
    float tm = NEG_INF;
    #pragma unroll
    for (int mt = 0; mt < 4; ++mt) {
        int qbase = q0 + wr * 64 + mt * 16 + lq * 4;
        #pragma unroll
        for (int reg = 0; reg < 4; ++reg) {
            if (qbase + reg < NF) {
                #pragma unroll
                for (int nt = 0; nt < 4; ++nt)
                    if (!mm[nt]) tm = fmaxf(tm, acc[mt][nt][reg]);
            }
        }
    }
    float ts = 0.f;
    if (tm != NEG_INF) {
        #pragma unroll
        for (int mt = 0; mt < 4; ++mt) {
            int qbase = q0 + wr * 64 + mt * 16 + lq * 4;
            #pragma unroll
            for (int reg = 0; reg < 4; ++reg) {
                if (qbase + reg < NF) {
                    #pragma unroll
                    for (int nt = 0; nt < 4; ++nt)
                        if (!mm[nt]) ts += __expf(acc[mt][nt][reg] - tm);
                }
            }
        }
    }

    // store raw (masked) scores
    #pragma unroll
    for (int mt = 0; mt < 4; ++mt) {
        #pragma unroll
        for (int reg = 0; reg < 4; ++reg) {
            int qg = q0 + wr * 64 + mt * 16 + lq * 4 + reg;
            if (qg < NF) {
                float* dst = out + (size_t)(b * ROWS + qg * NH + n) * HW + p0 + wc * 64 + lm;
                #pragma unroll
                for (int nt = 0; nt < 4; ++nt)
                    dst[nt * 16] = mm[nt] ? NEG_INF : acc[mt][nt][reg];
            }
        }
    }

    // block reduce (m, s) — reuse staging LDS (safe after last __syncthreads)
    float* redM = (float*)&Ah[0][0];
    float* redS = redM + 256;
    redM[t] = tm; redS[t] = ts;
    __syncthreads();
    for (int off = 128; off > 0; off >>= 1) {
        if (t < off) {
            float m1 = redM[t],       s1 = redS[t];
            float m2 = redM[t + off], s2 = redS[t + off];
            float M = fmaxf(m1, m2);
            float s = (M == NEG_INF) ? 0.f
                      : (s1 * __expf(m1 - M) + s2 * __expf(m2 - M));
            redM[t] = M; redS[t] = s;
        }
        __syncthreads();
    }
    if (t == 0) {
        int lin = (z * gridDim.y + blockIdx.y) * gridDim.x + blockIdx.x;
        partials[2 * lin]     = redM[0];
        partials[2 * lin + 1] = redS[0];
    }
}

// ---------------- K4: merge partials per batch -> (M_b, 1/S_b) -------------
__global__ __launch_bounds__(256) void stats_kernel(
    const float* __restrict__ partials, float* __restrict__ stats, int nper)
{
    __shared__ float redM[256];
    __shared__ float redS[256];
    const int b = blockIdx.x, t = threadIdx.x;
    const float* p = partials + (size_t)b * nper * 2;
    float m = NEG_INF, s = 0.f;
    for (int i = t; i < nper; i += 256) {
        float m2 = p[2 * i], s2 = p[2 * i + 1];
        float M = fmaxf(m, m2);
        float ns = (M == NEG_INF) ? 0.f
                   : (s * __expf(m - M) + s2 * __expf(m2 - M));
        m = M; s = ns;
    }
    redM[t] = m; redS[t] = s;
    __syncthreads();
    for (int off = 128; off > 0; off >>= 1) {
        if (t < off) {
            float m1 = redM[t],       s1 = redS[t];
            float m2 = redM[t + off], s2 = redS[t + off];
            float M = fmaxf(m1, m2);
            float ns = (M == NEG_INF) ? 0.f
                       : (s1 * __expf(m1 - M) + s2 * __expf(m2 - M));
            redM[t] = M; redS[t] = ns;
        }
        __syncthreads();
    }
    if (t == 0) {
        stats[2 * b]     = redM[0];
        stats[2 * b + 1] = 1.0f / redS[0];
    }
}

// ---------------- K5: normalize out = exp(s - M) / S ----------------------
__global__ __launch_bounds__(256) void norm_kernel(
    float* __restrict__ out, const float* __restrict__ stats)
{
    const int i4 = blockIdx.x * 256 + threadIdx.x;   // float4 index
    if (i4 >= (B_ * PB) / 4) return;
    const int b = i4 / (PB / 4);
    const float M    = stats[2 * b];
    const float invS = stats[2 * b + 1];
    float4 v = ((const float4*)out)[i4];
    v.x = __expf(v.x - M) * invS;
    v.y = __expf(v.y - M) * invS;
    v.z = __expf(v.z - M) * invS;
    v.w = __expf(v.w - M) * invS;
    ((float4*)out)[i4] = v;
}

extern "C" void kernel_launch(void* const* d_in, const int* in_sizes, int n_in,
                              void* d_out, int out_size, void* d_ws, size_t ws_size,
                              hipStream_t stream) {
    const float* q    = (const float*)d_in[0];  // [4,300,512]
    const float* k    = (const float*)d_in[1];  // [4,512,80,80]
    const int*   mask = (const int*)  d_in[2];  // [4,80,80]
    const float* qw   = (const float*)d_in[3];  // [512,512]
    const float* qb   = (const float*)d_in[4];  // [512]
    const float* kw   = (const float*)d_in[5];  // [512,512]
    const float* kb   = (const float*)d_in[6];  // [512]
    float* out = (float*)d_out;                 // [4,1,2400,80,80]
    float* ws  = (float*)d_ws;

    float* qh       = ws;              // 614,400 floats
    float* kp       = ws + 614400;     // 13,107,200 floats
    float* partials = ws + 13721600;   // 4800*2 floats
    float* stats    = ws + 13731200;   // 8 floats

    qproj_kernel<<<300, 256, 0, stream>>>(q, qw, qb, qh);
    kproj_mfma<<<dim3(50, 4, 4), 256, 0, stream>>>(k, kw, kb, kp);
    scores_mfma<<<dim3(50, 3, 32), 256, 0, stream>>>(qh, kp, mask, out, partials);
    stats_kernel<<<4, 256, 0, stream>>>(partials, stats, 1200);
    norm_kernel<<<60000, 256, 0, stream>>>(out, stats);
}

// Round 3
// 505.895 us; speedup vs baseline: 1.4491x; 1.1136x over previous
//
#include <hip/hip_runtime.h>
#include <math.h>

#define B_    4
#define NF    300
#define QD    512
#define HID   512
#define NH    8
#define HD    64
#define HW    6400      // 80*80
#define ROWS  2400      // NF*NH
#define PB    15360000  // ROWS*HW per batch
#define NORM_FACT 0.125f
#define NEG_INF (-INFINITY)
#define LDK   40        // padded LDS row (bf16) for a 32-wide k-chunk

typedef __bf16 bf16_t;
typedef __bf16 bf16x4_t __attribute__((ext_vector_type(4)));
typedef __bf16 bf16x8_t __attribute__((ext_vector_type(8)));
typedef float  f32x4    __attribute__((ext_vector_type(4)));

__device__ __forceinline__ void splitf(float x, bf16_t& h, bf16_t& l) {
    h = (bf16_t)x;
    l = (bf16_t)(x - (float)h);
}

// ---------------- K1: q projection  qh[b][q][e] = (q . q_w[e] + b) * 0.125 ----
__global__ __launch_bounds__(256) void qproj_kernel(
    const float* __restrict__ q, const float* __restrict__ qw,
    const float* __restrict__ qb, float* __restrict__ qh)
{
    __shared__ float qs[4][QD];
    const int r0 = blockIdx.x * 4;
    const int t  = threadIdx.x;
    #pragma unroll
    for (int row = 0; row < 4; ++row) {
        qs[row][t]       = q[(size_t)(r0 + row) * QD + t];
        qs[row][t + 256] = q[(size_t)(r0 + row) * QD + t + 256];
    }
    __syncthreads();
    #pragma unroll
    for (int eo = 0; eo < 2; ++eo) {
        const int e = t + eo * 256;
        float a0 = 0.f, a1 = 0.f, a2 = 0.f, a3 = 0.f;
        for (int d = 0; d < QD; d += 4) {
            float4 w = *(const float4*)&qw[(size_t)e * QD + d];
            a0 += qs[0][d]*w.x + qs[0][d+1]*w.y + qs[0][d+2]*w.z + qs[0][d+3]*w.w;
            a1 += qs[1][d]*w.x + qs[1][d+1]*w.y + qs[1][d+2]*w.z + qs[1][d+3]*w.w;
            a2 += qs[2][d]*w.x + qs[2][d+1]*w.y + qs[2][d+2]*w.z + qs[2][d+3]*w.w;
            a3 += qs[3][d]*w.x + qs[3][d+1]*w.y + qs[3][d+2]*w.z + qs[3][d+3]*w.w;
        }
        const float bias = qb[e];
        qh[(size_t)(r0+0)*HID + e] = (a0 + bias) * NORM_FACT;
        qh[(size_t)(r0+1)*HID + e] = (a1 + bias) * NORM_FACT;
        qh[(size_t)(r0+2)*HID + e] = (a2 + bias) * NORM_FACT;
        qh[(size_t)(r0+3)*HID + e] = (a3 + bias) * NORM_FACT;
    }
}

// ---------------- K2: k projection via split-bf16 MFMA ---------------------
__global__ __launch_bounds__(256) void kproj_mfma(
    const float* __restrict__ k, const float* __restrict__ kw,
    const float* __restrict__ kb, float* __restrict__ kp)
{
    __shared__ __align__(16) bf16_t Ah[128][LDK];
    __shared__ __align__(16) bf16_t Al[128][LDK];
    __shared__ __align__(16) bf16_t Bh[128][LDK];
    __shared__ __align__(16) bf16_t Bl[128][LDK];
    const int b  = blockIdx.z;
    const int e0 = blockIdx.y * 128;
    const int p0 = blockIdx.x * 128;
    const int t  = threadIdx.x;
    const int wave = t >> 6, lane = t & 63;
    const int wr = wave >> 1, wc = wave & 1;
    const int lm = lane & 15, lq = lane >> 4;
    const float* kB = k + (size_t)b * QD * HW;

    f32x4 acc[4][4];
    const f32x4 zero4 = {0.f, 0.f, 0.f, 0.f};
    #pragma unroll
    for (int i = 0; i < 4; ++i)
        #pragma unroll
        for (int j = 0; j < 4; ++j) acc[i][j] = zero4;

    for (int d0 = 0; d0 < QD; d0 += 32) {
        #pragma unroll
        for (int i = 0; i < 4; ++i) {
            int idx = t + i * 256;
            int e = idx >> 3, dp = (idx & 7) << 2;
            float4 v = *(const float4*)&kw[(size_t)(e0 + e) * QD + d0 + dp];
            bf16x4_t hv, lv; bf16_t hx, lx;
            splitf(v.x, hx, lx); hv[0] = hx; lv[0] = lx;
            splitf(v.y, hx, lx); hv[1] = hx; lv[1] = lx;
            splitf(v.z, hx, lx); hv[2] = hx; lv[2] = lx;
            splitf(v.w, hx, lx); hv[3] = hx; lv[3] = lx;
            *(bf16x4_t*)&Ah[e][dp] = hv;
            *(bf16x4_t*)&Al[e][dp] = lv;
        }
        #pragma unroll
        for (int i = 0; i < 4; ++i) {
            int idx = t + i * 256;
            int p = idx & 127, db = (idx >> 7) << 2;
            bf16x4_t hv, lv;
            #pragma unroll
            for (int j = 0; j < 4; ++j) {
                float x = kB[(size_t)(d0 + db + j) * HW + p0 + p];
                bf16_t hx, lx; splitf(x, hx, lx);
                hv[j] = hx; lv[j] = lx;
            }
            *(bf16x4_t*)&Bh[p][db] = hv;
            *(bf16x4_t*)&Bl[p][db] = lv;
        }
        __syncthreads();

        bf16x8_t ah[4], al[4], bh[4], bl[4];
        #pragma unroll
        for (int mt = 0; mt < 4; ++mt) {
            int r = wr * 64 + mt * 16 + lm;
            ah[mt] = *(const bf16x8_t*)&Ah[r][lq * 8];
            al[mt] = *(const bf16x8_t*)&Al[r][lq * 8];
        }
        #pragma unroll
        for (int nt = 0; nt < 4; ++nt) {
            int c = wc * 64 + nt * 16 + lm;
            bh[nt] = *(const bf16x8_t*)&Bh[c][lq * 8];
            bl[nt] = *(const bf16x8_t*)&Bl[c][lq * 8];
        }
        #pragma unroll
        for (int mt = 0; mt < 4; ++mt)
            #pragma unroll
            for (int nt = 0; nt < 4; ++nt) {
                f32x4 a = acc[mt][nt];
                a = __builtin_amdgcn_mfma_f32_16x16x32_bf16(al[mt], bh[nt], a, 0, 0, 0);
                a = __builtin_amdgcn_mfma_f32_16x16x32_bf16(ah[mt], bl[nt], a, 0, 0, 0);
                a = __builtin_amdgcn_mfma_f32_16x16x32_bf16(ah[mt], bh[nt], a, 0, 0, 0);
                acc[mt][nt] = a;
            }
        __syncthreads();
    }

    #pragma unroll
    for (int mt = 0; mt < 4; ++mt) {
        #pragma unroll
        for (int reg = 0; reg < 4; ++reg) {
            int e = e0 + wr * 64 + mt * 16 + lq * 4 + reg;
            float bias = kb[e];
            float* dst = kp + (size_t)b * HID * HW + (size_t)e * HW + p0 + wc * 64 + lm;
            #pragma unroll
            for (int nt = 0; nt < 4; ++nt)
                dst[nt * 16] = acc[mt][nt][reg] + bias;
        }
    }
}

// ---------------- K3a: pass A — pure-bf16 score GEMM, (m,s) partials only ---
// M cancels exactly in exp(sB-M)/sum(exp(sA-M)); random bf16 errors in sA
// average out inside the weighted sum S -> pure bf16 is safe here.
__global__ __launch_bounds__(256) void scores_pass_a(
    const float* __restrict__ qh, const float* __restrict__ kp,
    const int* __restrict__ mask, float* __restrict__ partials)
{
    __shared__ __align__(16) bf16_t Ah[128][LDK];
    __shared__ __align__(16) bf16_t Bh[128][LDK];
    __shared__ float redM[256];
    __shared__ float redS[256];
    const int z  = blockIdx.z;
    const int b  = z >> 3, n = z & 7;
    const int q0 = blockIdx.y * 128;
    const int p0 = blockIdx.x * 128;
    const int t  = threadIdx.x;
    const int wave = t >> 6, lane = t & 63;
    const int wr = wave >> 1, wc = wave & 1;
    const int lm = lane & 15, lq = lane >> 4;

    f32x4 acc[4][4];
    const f32x4 zero4 = {0.f, 0.f, 0.f, 0.f};
    #pragma unroll
    for (int i = 0; i < 4; ++i)
        #pragma unroll
        for (int j = 0; j < 4; ++j) acc[i][j] = zero4;

    for (int d0 = 0; d0 < HD; d0 += 32) {
        #pragma unroll
        for (int i = 0; i < 4; ++i) {
            int idx = t + i * 256;
            int qq = idx >> 3, dp = (idx & 7) << 2;
            int qg = q0 + qq;
            float4 v = make_float4(0.f, 0.f, 0.f, 0.f);
            if (qg < NF)
                v = *(const float4*)&qh[(size_t)(b * NF + qg) * HID + n * HD + d0 + dp];
            bf16x4_t hv;
            hv[0] = (bf16_t)v.x; hv[1] = (bf16_t)v.y;
            hv[2] = (bf16_t)v.z; hv[3] = (bf16_t)v.w;
            *(bf16x4_t*)&Ah[qq][dp] = hv;
        }
        const float* kpB = kp + (size_t)b * HID * HW + (size_t)(n * HD + d0) * HW;
        #pragma unroll
        for (int i = 0; i < 4; ++i) {
            int idx = t + i * 256;
            int p = idx & 127, db = (idx >> 7) << 2;
            bf16x4_t hv;
            #pragma unroll
            for (int j = 0; j < 4; ++j)
                hv[j] = (bf16_t)kpB[(size_t)(db + j) * HW + p0 + p];
            *(bf16x4_t*)&Bh[p][db] = hv;
        }
        __syncthreads();

        bf16x8_t ah[4], bh[4];
        #pragma unroll
        for (int mt = 0; mt < 4; ++mt)
            ah[mt] = *(const bf16x8_t*)&Ah[wr * 64 + mt * 16 + lm][lq * 8];
        #pragma unroll
        for (int nt = 0; nt < 4; ++nt)
            bh[nt] = *(const bf16x8_t*)&Bh[wc * 64 + nt * 16 + lm][lq * 8];
        #pragma unroll
        for (int mt = 0; mt < 4; ++mt)
            #pragma unroll
            for (int nt = 0; nt < 4; ++nt)
                acc[mt][nt] = __builtin_amdgcn_mfma_f32_16x16x32_bf16(
                    ah[mt], bh[nt], acc[mt][nt], 0, 0, 0);
        __syncthreads();
    }

    int mm[4];
    #pragma unroll
    for (int nt = 0; nt < 4; ++nt)
        mm[nt] = mask[b * HW + p0 + wc * 64 + nt * 16 + lm];

    float tm = NEG_INF;
    #pragma unroll
    for (int mt = 0; mt < 4; ++mt) {
        int qbase = q0 + wr * 64 + mt * 16 + lq * 4;
        #pragma unroll
        for (int reg = 0; reg < 4; ++reg) {
            if (qbase + reg < NF) {
                #pragma unroll
                for (int nt = 0; nt < 4; ++nt)
                    if (!mm[nt]) tm = fmaxf(tm, acc[mt][nt][reg]);
            }
        }
    }
    float ts = 0.f;
    if (tm != NEG_INF) {
        #pragma unroll
        for (int mt = 0; mt < 4; ++mt) {
            int qbase = q0 + wr * 64 + mt * 16 + lq * 4;
            #pragma unroll
            for (int reg = 0; reg < 4; ++reg) {
                if (qbase + reg < NF) {
                    #pragma unroll
                    for (int nt = 0; nt < 4; ++nt)
                        if (!mm[nt]) ts += __expf(acc[mt][nt][reg] - tm);
                }
            }
        }
    }

    redM[t] = tm; redS[t] = ts;
    __syncthreads();
    for (int off = 128; off > 0; off >>= 1) {
        if (t < off) {
            float m1 = redM[t],       s1 = redS[t];
            float m2 = redM[t + off], s2 = redS[t + off];
            float M = fmaxf(m1, m2);
            float s = (M == NEG_INF) ? 0.f
                      : (s1 * __expf(m1 - M) + s2 * __expf(m2 - M));
            redM[t] = M; redS[t] = s;
        }
        __syncthreads();
    }
    if (t == 0) {
        int lin = (z * gridDim.y + blockIdx.y) * gridDim.x + blockIdx.x;
        partials[2 * lin]     = redM[0];
        partials[2 * lin + 1] = redS[0];
    }
}

// ---------------- K4: merge partials per batch -> (M_b, 1/S_b) -------------
__global__ __launch_bounds__(256) void stats_kernel(
    const float* __restrict__ partials, float* __restrict__ stats, int nper)
{
    __shared__ float redM[256];
    __shared__ float redS[256];
    const int b = blockIdx.x, t = threadIdx.x;
    const float* p = partials + (size_t)b * nper * 2;
    float m = NEG_INF, s = 0.f;
    for (int i = t; i < nper; i += 256) {
        float m2 = p[2 * i], s2 = p[2 * i + 1];
        float M = fmaxf(m, m2);
        float ns = (M == NEG_INF) ? 0.f
                   : (s * __expf(m - M) + s2 * __expf(m2 - M));
        m = M; s = ns;
    }
    redM[t] = m; redS[t] = s;
    __syncthreads();
    for (int off = 128; off > 0; off >>= 1) {
        if (t < off) {
            float m1 = redM[t],       s1 = redS[t];
            float m2 = redM[t + off], s2 = redS[t + off];
            float M = fmaxf(m1, m2);
            float ns = (M == NEG_INF) ? 0.f
                       : (s1 * __expf(m1 - M) + s2 * __expf(m2 - M));
            redM[t] = M; redS[t] = ns;
        }
        __syncthreads();
    }
    if (t == 0) {
        stats[2 * b]     = redM[0];
        stats[2 * b + 1] = 1.0f / redS[0];
    }
}

// ---------------- K3b: pass B — split-bf16 score GEMM, write exp(s-M)/S ----
__global__ __launch_bounds__(256) void scores_pass_b(
    const float* __restrict__ qh, const float* __restrict__ kp,
    const int* __restrict__ mask, const float* __restrict__ stats,
    float* __restrict__ out)
{
    __shared__ __align__(16) bf16_t Ah[128][LDK];
    __shared__ __align__(16) bf16_t Al[128][LDK];
    __shared__ __align__(16) bf16_t Bh[128][LDK];
    __shared__ __align__(16) bf16_t Bl[128][LDK];
    const int z  = blockIdx.z;
    const int b  = z >> 3, n = z & 7;
    const int q0 = blockIdx.y * 128;
    const int p0 = blockIdx.x * 128;
    const int t  = threadIdx.x;
    const int wave = t >> 6, lane = t & 63;
    const int wr = wave >> 1, wc = wave & 1;
    const int lm = lane & 15, lq = lane >> 4;

    const float M    = stats[2 * b];
    const float invS = stats[2 * b + 1];

    f32x4 acc[4][4];
    const f32x4 zero4 = {0.f, 0.f, 0.f, 0.f};
    #pragma unroll
    for (int i = 0; i < 4; ++i)
        #pragma unroll
        for (int j = 0; j < 4; ++j) acc[i][j] = zero4;

    for (int d0 = 0; d0 < HD; d0 += 32) {
        #pragma unroll
        for (int i = 0; i < 4; ++i) {
            int idx = t + i * 256;
            int qq = idx >> 3, dp = (idx & 7) << 2;
            int qg = q0 + qq;
            float4 v = make_float4(0.f, 0.f, 0.f, 0.f);
            if (qg < NF)
                v = *(const float4*)&qh[(size_t)(b * NF + qg) * HID + n * HD + d0 + dp];
            bf16x4_t hv, lv; bf16_t hx, lx;
            splitf(v.x, hx, lx); hv[0] = hx; lv[0] = lx;
            splitf(v.y, hx, lx); hv[1] = hx; lv[1] = lx;
            splitf(v.z, hx, lx); hv[2] = hx; lv[2] = lx;
            splitf(v.w, hx, lx); hv[3] = hx; lv[3] = lx;
            *(bf16x4_t*)&Ah[qq][dp] = hv;
            *(bf16x4_t*)&Al[qq][dp] = lv;
        }
        const float* kpB = kp + (size_t)b * HID * HW + (size_t)(n * HD + d0) * HW;
        #pragma unroll
        for (int i = 0; i < 4; ++i) {
            int idx = t + i * 256;
            int p = idx & 127, db = (idx >> 7) << 2;
            bf16x4_t hv, lv;
            #pragma unroll
            for (int j = 0; j < 4; ++j) {
                float x = kpB[(size_t)(db + j) * HW + p0 + p];
                bf16_t hx, lx; splitf(x, hx, lx);
                hv[j] = hx; lv[j] = lx;
            }
            *(bf16x4_t*)&Bh[p][db] = hv;
            *(bf16x4_t*)&Bl[p][db] = lv;
        }
        __syncthreads();

        bf16x8_t ah[4], al[4], bh[4], bl[4];
        #pragma unroll
        for (int mt = 0; mt < 4; ++mt) {
            int r = wr * 64 + mt * 16 + lm;
            ah[mt] = *(const bf16x8_t*)&Ah[r][lq * 8];
            al[mt] = *(const bf16x8_t*)&Al[r][lq * 8];
        }
        #pragma unroll
        for (int nt = 0; nt < 4; ++nt) {
            int c = wc * 64 + nt * 16 + lm;
            bh[nt] = *(const bf16x8_t*)&Bh[c][lq * 8];
            bl[nt] = *(const bf16x8_t*)&Bl[c][lq * 8];
        }
        #pragma unroll
        for (int mt = 0; mt < 4; ++mt)
            #pragma unroll
            for (int nt = 0; nt < 4; ++nt) {
                f32x4 a = acc[mt][nt];
                a = __builtin_amdgcn_mfma_f32_16x16x32_bf16(al[mt], bh[nt], a, 0, 0, 0);
                a = __builtin_amdgcn_mfma_f32_16x16x32_bf16(ah[mt], bl[nt], a, 0, 0, 0);
                a = __builtin_amdgcn_mfma_f32_16x16x32_bf16(ah[mt], bh[nt], a, 0, 0, 0);
                acc[mt][nt] = a;
            }
        __syncthreads();
    }

    int mm[4];
    #pragma unroll
    for (int nt = 0; nt < 4; ++nt)
        mm[nt] = mask[b * HW + p0 + wc * 64 + nt * 16 + lm];

    #pragma unroll
    for (int mt = 0; mt < 4; ++mt) {
        #pragma unroll
        for (int reg = 0; reg < 4; ++reg) {
            int qg = q0 + wr * 64 + mt * 16 + lq * 4 + reg;
            if (qg < NF) {
                float* dst = out + (size_t)(b * ROWS + qg * NH + n) * HW + p0 + wc * 64 + lm;
                #pragma unroll
                for (int nt = 0; nt < 4; ++nt)
                    dst[nt * 16] = mm[nt] ? 0.f : __expf(acc[mt][nt][reg] - M) * invS;
            }
        }
    }
}

extern "C" void kernel_launch(void* const* d_in, const int* in_sizes, int n_in,
                              void* d_out, int out_size, void* d_ws, size_t ws_size,
                              hipStream_t stream) {
    const float* q    = (const float*)d_in[0];  // [4,300,512]
    const float* k    = (const float*)d_in[1];  // [4,512,80,80]
    const int*   mask = (const int*)  d_in[2];  // [4,80,80]
    const float* qw   = (const float*)d_in[3];  // [512,512]
    const float* qb   = (const float*)d_in[4];  // [512]
    const float* kw   = (const float*)d_in[5];  // [512,512]
    const float* kb   = (const float*)d_in[6];  // [512]
    float* out = (float*)d_out;                 // [4,1,2400,80,80]
    float* ws  = (float*)d_ws;

    float* qh       = ws;              // 614,400 floats
    float* kp       = ws + 614400;     // 13,107,200 floats
    float* partials = ws + 13721600;   // 4800*2 floats
    float* stats    = ws + 13731200;   // 8 floats

    qproj_kernel<<<300, 256, 0, stream>>>(q, qw, qb, qh);
    kproj_mfma<<<dim3(50, 4, 4), 256, 0, stream>>>(k, kw, kb, kp);
    scores_pass_a<<<dim3(50, 3, 32), 256, 0, stream>>>(qh, kp, mask, partials);
    stats_kernel<<<4, 256, 0, stream>>>(partials, stats, 1200);
    scores_pass_b<<<dim3(50, 3, 32), 256, 0, stream>>>(qh, kp, mask, stats, out);
}

// Round 4
// 503.566 us; speedup vs baseline: 1.4558x; 1.0046x over previous
//
#include <hip/hip_runtime.h>
#include <math.h>

#define B_    4
#define NF    300
#define QD    512
#define HID   512
#define NH    8
#define HD    64
#define HW    6400      // 80*80
#define ROWS  2400      // NF*NH
#define NQP   384       // padded q rows per (b,n) block (3 tiles of 128)
#define NORM_FACT 0.125f
#define NEG_INF (-INFINITY)
#define LDK   40        // padded LDS row (bf16) for kproj 32-wide k-chunks

typedef __bf16 bf16_t;
typedef __bf16 bf16x4_t __attribute__((ext_vector_type(4)));
typedef __bf16 bf16x8_t __attribute__((ext_vector_type(8)));
typedef float  f32x4    __attribute__((ext_vector_type(4)));

__device__ __forceinline__ void splitf(float x, bf16_t& h, bf16_t& l) {
    h = (bf16_t)x;
    l = (bf16_t)(x - (float)h);
}
// swizzle: permute 16B c-blocks within a 128B row by row&7 (conflict-free frags)
__device__ __forceinline__ int swz(int c, int row) {
    return (((c >> 3) ^ (row & 7)) << 3) | (c & 7);
}

// ---------------- K1: q projection -> bf16 hi/lo planes [b][n][q][64c swz] --
__global__ __launch_bounds__(256) void qproj_kernel(
    const float* __restrict__ q, const float* __restrict__ qw,
    const float* __restrict__ qb, bf16_t* __restrict__ qh_hi,
    bf16_t* __restrict__ qh_lo)
{
    __shared__ float qs[4][QD];
    const int r0    = blockIdx.x * 4;          // rows in (b*NF+q) space; NF%4==0
    const int b     = r0 / NF;
    const int qbase = r0 % NF;
    const int t     = threadIdx.x;
    #pragma unroll
    for (int row = 0; row < 4; ++row) {
        qs[row][t]       = q[(size_t)(r0 + row) * QD + t];
        qs[row][t + 256] = q[(size_t)(r0 + row) * QD + t + 256];
    }
    __syncthreads();
    #pragma unroll
    for (int eo = 0; eo < 2; ++eo) {
        const int e = t + eo * 256;
        const int n = e >> 6, c = e & 63;
        float a[4] = {0.f, 0.f, 0.f, 0.f};
        for (int d = 0; d < QD; d += 4) {
            float4 w = *(const float4*)&qw[(size_t)e * QD + d];
            #pragma unroll
            for (int row = 0; row < 4; ++row)
                a[row] += qs[row][d]*w.x + qs[row][d+1]*w.y
                        + qs[row][d+2]*w.z + qs[row][d+3]*w.w;
        }
        const float bias = qb[e];
        #pragma unroll
        for (int row = 0; row < 4; ++row) {
            const int qq = qbase + row;
            const float val = (a[row] + bias) * NORM_FACT;
            bf16_t h, l; splitf(val, h, l);
            size_t off = ((size_t)(b * NH + n) * NQP + qq) * 64 + swz(c, qq);
            qh_hi[off] = h; qh_lo[off] = l;
        }
    }
}

// ---------------- K2: k projection (M=p, N=e) -> bf16 hi/lo planes ---------
// C'[p][e] = K^T[p][d] * W^T[d][e] + kb; stored [b][n][p][64c swz]
__global__ __launch_bounds__(256) void kproj_mfma(
    const float* __restrict__ k, const float* __restrict__ kw,
    const float* __restrict__ kb, bf16_t* __restrict__ kp_hi,
    bf16_t* __restrict__ kp_lo)
{
    __shared__ __align__(16) bf16_t Ah[128][LDK];  // K^T rows: [p][d-chunk]
    __shared__ __align__(16) bf16_t Al[128][LDK];
    __shared__ __align__(16) bf16_t Bh[128][LDK];  // W rows:   [e][d-chunk]
    __shared__ __align__(16) bf16_t Bl[128][LDK];
    const int b  = blockIdx.z;
    const int e0 = blockIdx.y * 128;
    const int p0 = blockIdx.x * 128;
    const int t  = threadIdx.x;
    const int wave = t >> 6, lane = t & 63;
    const int wr = wave >> 1, wc = wave & 1;       // wr: p-half, wc: e-half
    const int lm = lane & 15, lq = lane >> 4;
    const float* kB = k + (size_t)b * QD * HW;

    f32x4 acc[4][4];
    const f32x4 zero4 = {0.f, 0.f, 0.f, 0.f};
    #pragma unroll
    for (int i = 0; i < 4; ++i)
        #pragma unroll
        for (int j = 0; j < 4; ++j) acc[i][j] = zero4;

    for (int d0 = 0; d0 < QD; d0 += 32) {
        // A = K^T: transpose-stage K[d][p] -> LDS [p][d]
        #pragma unroll
        for (int i = 0; i < 4; ++i) {
            int idx = t + i * 256;
            int p = idx & 127, db = (idx >> 7) << 2;
            bf16x4_t hv, lv;
            #pragma unroll
            for (int j = 0; j < 4; ++j) {
                float x = kB[(size_t)(d0 + db + j) * HW + p0 + p];
                bf16_t hx, lx; splitf(x, hx, lx);
                hv[j] = hx; lv[j] = lx;
            }
            *(bf16x4_t*)&Ah[p][db] = hv;
            *(bf16x4_t*)&Al[p][db] = lv;
        }
        // B = W: rows are already d-contiguous
        #pragma unroll
        for (int i = 0; i < 4; ++i) {
            int idx = t + i * 256;
            int e = idx >> 3, dp = (idx & 7) << 2;
            float4 v = *(const float4*)&kw[(size_t)(e0 + e) * QD + d0 + dp];
            bf16x4_t hv, lv; bf16_t hx, lx;
            splitf(v.x, hx, lx); hv[0] = hx; lv[0] = lx;
            splitf(v.y, hx, lx); hv[1] = hx; lv[1] = lx;
            splitf(v.z, hx, lx); hv[2] = hx; lv[2] = lx;
            splitf(v.w, hx, lx); hv[3] = hx; lv[3] = lx;
            *(bf16x4_t*)&Bh[e][dp] = hv;
            *(bf16x4_t*)&Bl[e][dp] = lv;
        }
        __syncthreads();

        bf16x8_t ah[4], al[4], bh[4], bl[4];
        #pragma unroll
        for (int mt = 0; mt < 4; ++mt) {
            int r = wr * 64 + mt * 16 + lm;
            ah[mt] = *(const bf16x8_t*)&Ah[r][lq * 8];
            al[mt] = *(const bf16x8_t*)&Al[r][lq * 8];
        }
        #pragma unroll
        for (int nt = 0; nt < 4; ++nt) {
            int c = wc * 64 + nt * 16 + lm;
            bh[nt] = *(const bf16x8_t*)&Bh[c][lq * 8];
            bl[nt] = *(const bf16x8_t*)&Bl[c][lq * 8];
        }
        #pragma unroll
        for (int mt = 0; mt < 4; ++mt)
            #pragma unroll
            for (int nt = 0; nt < 4; ++nt) {
                f32x4 a = acc[mt][nt];
                a = __builtin_amdgcn_mfma_f32_16x16x32_bf16(al[mt], bh[nt], a, 0, 0, 0);
                a = __builtin_amdgcn_mfma_f32_16x16x32_bf16(ah[mt], bl[nt], a, 0, 0, 0);
                a = __builtin_amdgcn_mfma_f32_16x16x32_bf16(ah[mt], bh[nt], a, 0, 0, 0);
                acc[mt][nt] = a;
            }
        __syncthreads();
    }

    // epilogue: lane axis = e (col), reg axis = p (row) -> c-contiguous stores
    #pragma unroll
    for (int nt = 0; nt < 4; ++nt) {
        const int e = e0 + wc * 64 + nt * 16 + lm;
        const int n = e >> 6;
        const int c = (nt * 16 + lm) & 63;     // == e & 63
        const float bias = kb[e];
        bf16_t* dh = kp_hi + (size_t)(b * NH + n) * HW * 64;
        bf16_t* dl = kp_lo + (size_t)(b * NH + n) * HW * 64;
        #pragma unroll
        for (int mt = 0; mt < 4; ++mt) {
            #pragma unroll
            for (int reg = 0; reg < 4; ++reg) {
                int p = p0 + wr * 64 + mt * 16 + lq * 4 + reg;
                float val = acc[mt][nt][reg] + bias;
                bf16_t h, l; splitf(val, h, l);
                size_t off = (size_t)p * 64 + swz(c, p);
                dh[off] = h; dl[off] = l;
            }
        }
    }
}

// ---------------- K3a: pass A — hi-plane bf16 score GEMM, (m,s) partials ----
__global__ __launch_bounds__(256) void scores_pass_a(
    const bf16_t* __restrict__ qh_hi, const bf16_t* __restrict__ kp_hi,
    const int* __restrict__ mask, float* __restrict__ partials)
{
    __shared__ __align__(16) bf16_t At[128 * 64];
    __shared__ __align__(16) bf16_t Bt[128 * 64];
    __shared__ float redM[256];
    __shared__ float redS[256];
    const int z  = blockIdx.z;
    const int b  = z >> 3, n = z & 7;
    const int q0 = blockIdx.y * 128;
    const int p0 = blockIdx.x * 128;
    const int t  = threadIdx.x;
    const int wave = t >> 6, lane = t & 63;
    const int wr = wave >> 1, wc = wave & 1;
    const int lm = lane & 15, lq = lane >> 4;

    // staging = pure 16B copies (layout is pre-transposed, pre-swizzled)
    const uint4* ga = (const uint4*)(qh_hi + ((size_t)(b * NH + n) * NQP + q0) * 64);
    const uint4* gb = (const uint4*)(kp_hi + ((size_t)(b * NH + n) * HW  + p0) * 64);
    uint4* la = (uint4*)At;
    uint4* lb = (uint4*)Bt;
    #pragma unroll
    for (int i = 0; i < 4; ++i) {
        la[t + i * 256] = ga[t + i * 256];
        lb[t + i * 256] = gb[t + i * 256];
    }
    __syncthreads();

    f32x4 acc[4][4];
    const f32x4 zero4 = {0.f, 0.f, 0.f, 0.f};
    #pragma unroll
    for (int i = 0; i < 4; ++i)
        #pragma unroll
        for (int j = 0; j < 4; ++j) acc[i][j] = zero4;

    #pragma unroll
    for (int ks = 0; ks < 2; ++ks) {
        bf16x8_t af[4], bf[4];
        #pragma unroll
        for (int mt = 0; mt < 4; ++mt) {
            int row = wr * 64 + mt * 16 + lm;
            af[mt] = *(const bf16x8_t*)&At[row * 64 + (((lq + ks * 4) ^ (lm & 7)) << 3)];
        }
        #pragma unroll
        for (int nt = 0; nt < 4; ++nt) {
            int row = wc * 64 + nt * 16 + lm;
            bf[nt] = *(const bf16x8_t*)&Bt[row * 64 + (((lq + ks * 4) ^ (lm & 7)) << 3)];
        }
        #pragma unroll
        for (int mt = 0; mt < 4; ++mt)
            #pragma unroll
            for (int nt = 0; nt < 4; ++nt)
                acc[mt][nt] = __builtin_amdgcn_mfma_f32_16x16x32_bf16(
                    af[mt], bf[nt], acc[mt][nt], 0, 0, 0);
    }

    int mm[4];
    #pragma unroll
    for (int nt = 0; nt < 4; ++nt)
        mm[nt] = mask[b * HW + p0 + wc * 64 + nt * 16 + lm];

    float tm = NEG_INF;
    #pragma unroll
    for (int mt = 0; mt < 4; ++mt) {
        int qbase = q0 + wr * 64 + mt * 16 + lq * 4;
        #pragma unroll
        for (int reg = 0; reg < 4; ++reg) {
            if (qbase + reg < NF) {
                #pragma unroll
                for (int nt = 0; nt < 4; ++nt)
                    if (!mm[nt]) tm = fmaxf(tm, acc[mt][nt][reg]);
            }
        }
    }
    float ts = 0.f;
    if (tm != NEG_INF) {
        #pragma unroll
        for (int mt = 0; mt < 4; ++mt) {
            int qbase = q0 + wr * 64 + mt * 16 + lq * 4;
            #pragma unroll
            for (int reg = 0; reg < 4; ++reg) {
                if (qbase + reg < NF) {
                    #pragma unroll
                    for (int nt = 0; nt < 4; ++nt)
                        if (!mm[nt]) ts += __expf(acc[mt][nt][reg] - tm);
                }
            }
        }
    }

    redM[t] = tm; redS[t] = ts;
    __syncthreads();
    for (int off = 128; off > 0; off >>= 1) {
        if (t < off) {
            float m1 = redM[t],       s1 = redS[t];
            float m2 = redM[t + off], s2 = redS[t + off];
            float M = fmaxf(m1, m2);
            float s = (M == NEG_INF) ? 0.f
                      : (s1 * __expf(m1 - M) + s2 * __expf(m2 - M));
            redM[t] = M; redS[t] = s;
        }
        __syncthreads();
    }
    if (t == 0) {
        int lin = (z * gridDim.y + blockIdx.y) * gridDim.x + blockIdx.x;
        partials[2 * lin]     = redM[0];
        partials[2 * lin + 1] = redS[0];
    }
}

// ---------------- K4: merge partials per batch -> (M_b, 1/S_b) -------------
__global__ __launch_bounds__(256) void stats_kernel(
    const float* __restrict__ partials, float* __restrict__ stats, int nper)
{
    __shared__ float redM[256];
    __shared__ float redS[256];
    const int b = blockIdx.x, t = threadIdx.x;
    const float* p = partials + (size_t)b * nper * 2;
    float m = NEG_INF, s = 0.f;
    for (int i = t; i < nper; i += 256) {
        float m2 = p[2 * i], s2 = p[2 * i + 1];
        float M = fmaxf(m, m2);
        float ns = (M == NEG_INF) ? 0.f
                   : (s * __expf(m - M) + s2 * __expf(m2 - M));
        m = M; s = ns;
    }
    redM[t] = m; redS[t] = s;
    __syncthreads();
    for (int off = 128; off > 0; off >>= 1) {
        if (t < off) {
            float m1 = redM[t],       s1 = redS[t];
            float m2 = redM[t + off], s2 = redS[t + off];
            float M = fmaxf(m1, m2);
            float ns = (M == NEG_INF) ? 0.f
                       : (s1 * __expf(m1 - M) + s2 * __expf(m2 - M));
            redM[t] = M; redS[t] = ns;
        }
        __syncthreads();
    }
    if (t == 0) {
        stats[2 * b]     = redM[0];
        stats[2 * b + 1] = 1.0f / redS[0];
    }
}

// ---------------- K3b: pass B — split-bf16 score GEMM, write exp(s-M)/S ----
__global__ __launch_bounds__(256) void scores_pass_b(
    const bf16_t* __restrict__ qh_hi, const bf16_t* __restrict__ qh_lo,
    const bf16_t* __restrict__ kp_hi, const bf16_t* __restrict__ kp_lo,
    const int* __restrict__ mask, const float* __restrict__ stats,
    float* __restrict__ out)
{
    __shared__ __align__(16) bf16_t Aht[128 * 64];
    __shared__ __align__(16) bf16_t Alt[128 * 64];
    __shared__ __align__(16) bf16_t Bht[128 * 64];
    __shared__ __align__(16) bf16_t Blt[128 * 64];
    const int z  = blockIdx.z;
    const int b  = z >> 3, n = z & 7;
    const int q0 = blockIdx.y * 128;
    const int p0 = blockIdx.x * 128;
    const int t  = threadIdx.x;
    const int wave = t >> 6, lane = t & 63;
    const int wr = wave >> 1, wc = wave & 1;
    const int lm = lane & 15, lq = lane >> 4;

    const float M    = stats[2 * b];
    const float invS = stats[2 * b + 1];

    const size_t abase = ((size_t)(b * NH + n) * NQP + q0) * 64;
    const size_t bbase = ((size_t)(b * NH + n) * HW  + p0) * 64;
    const uint4* gah = (const uint4*)(qh_hi + abase);
    const uint4* gal = (const uint4*)(qh_lo + abase);
    const uint4* gbh = (const uint4*)(kp_hi + bbase);
    const uint4* gbl = (const uint4*)(kp_lo + bbase);
    #pragma unroll
    for (int i = 0; i < 4; ++i) {
        ((uint4*)Aht)[t + i * 256] = gah[t + i * 256];
        ((uint4*)Alt)[t + i * 256] = gal[t + i * 256];
        ((uint4*)Bht)[t + i * 256] = gbh[t + i * 256];
        ((uint4*)Blt)[t + i * 256] = gbl[t + i * 256];
    }
    __syncthreads();

    f32x4 acc[4][4];
    const f32x4 zero4 = {0.f, 0.f, 0.f, 0.f};
    #pragma unroll
    for (int i = 0; i < 4; ++i)
        #pragma unroll
        for (int j = 0; j < 4; ++j) acc[i][j] = zero4;

    #pragma unroll
    for (int ks = 0; ks < 2; ++ks) {
        bf16x8_t ah[4], al[4], bh[4], bl[4];
        #pragma unroll
        for (int mt = 0; mt < 4; ++mt) {
            int row = wr * 64 + mt * 16 + lm;
            int off = row * 64 + (((lq + ks * 4) ^ (lm & 7)) << 3);
            ah[mt] = *(const bf16x8_t*)&Aht[off];
            al[mt] = *(const bf16x8_t*)&Alt[off];
        }
        #pragma unroll
        for (int nt = 0; nt < 4; ++nt) {
            int row = wc * 64 + nt * 16 + lm;
            int off = row * 64 + (((lq + ks * 4) ^ (lm & 7)) << 3);
            bh[nt] = *(const bf16x8_t*)&Bht[off];
            bl[nt] = *(const bf16x8_t*)&Blt[off];
        }
        #pragma unroll
        for (int mt = 0; mt < 4; ++mt)
            #pragma unroll
            for (int nt = 0; nt < 4; ++nt) {
                f32x4 a = acc[mt][nt];
                a = __builtin_amdgcn_mfma_f32_16x16x32_bf16(al[mt], bh[nt], a, 0, 0, 0);
                a = __builtin_amdgcn_mfma_f32_16x16x32_bf16(ah[mt], bl[nt], a, 0, 0, 0);
                a = __builtin_amdgcn_mfma_f32_16x16x32_bf16(ah[mt], bh[nt], a, 0, 0, 0);
                acc[mt][nt] = a;
            }
    }

    int mm[4];
    #pragma unroll
    for (int nt = 0; nt < 4; ++nt)
        mm[nt] = mask[b * HW + p0 + wc * 64 + nt * 16 + lm];

    #pragma unroll
    for (int mt = 0; mt < 4; ++mt) {
        #pragma unroll
        for (int reg = 0; reg < 4; ++reg) {
            int qg = q0 + wr * 64 + mt * 16 + lq * 4 + reg;
            if (qg < NF) {
                float* dst = out + (size_t)(b * ROWS + qg * NH + n) * HW + p0 + wc * 64 + lm;
                #pragma unroll
                for (int nt = 0; nt < 4; ++nt)
                    dst[nt * 16] = mm[nt] ? 0.f : __expf(acc[mt][nt][reg] - M) * invS;
            }
        }
    }
}

extern "C" void kernel_launch(void* const* d_in, const int* in_sizes, int n_in,
                              void* d_out, int out_size, void* d_ws, size_t ws_size,
                              hipStream_t stream) {
    const float* q    = (const float*)d_in[0];  // [4,300,512]
    const float* k    = (const float*)d_in[1];  // [4,512,80,80]
    const int*   mask = (const int*)  d_in[2];  // [4,80,80]
    const float* qw   = (const float*)d_in[3];  // [512,512]
    const float* qb   = (const float*)d_in[4];  // [512]
    const float* kw   = (const float*)d_in[5];  // [512,512]
    const float* kb   = (const float*)d_in[6];  // [512]
    float* out = (float*)d_out;                 // [4,1,2400,80,80]

    // workspace layout (bf16 planes + fp32 reductions), ~55.6 MB
    bf16_t* kp_hi = (bf16_t*)d_ws;
    bf16_t* kp_lo = kp_hi + (size_t)B_ * NH * HW * 64;
    bf16_t* qh_hi = kp_lo + (size_t)B_ * NH * HW * 64;
    bf16_t* qh_lo = qh_hi + (size_t)B_ * NH * NQP * 64;
    float* partials = (float*)(qh_lo + (size_t)B_ * NH * NQP * 64);
    float* stats    = partials + 2 * 4800;

    qproj_kernel<<<300, 256, 0, stream>>>(q, qw, qb, qh_hi, qh_lo);
    kproj_mfma<<<dim3(50, 4, 4), 256, 0, stream>>>(k, kw, kb, kp_hi, kp_lo);
    scores_pass_a<<<dim3(50, 3, 32), 256, 0, stream>>>(qh_hi, kp_hi, mask, partials);
    stats_kernel<<<4, 256, 0, stream>>>(partials, stats, 1200);
    scores_pass_b<<<dim3(50, 3, 32), 256, 0, stream>>>(qh_hi, qh_lo, kp_hi, kp_lo,
                                                       mask, stats, out);
}